// Round 5
// baseline (451.727 us; speedup 1.0000x reference)
//
#include <hip/hip_runtime.h>
#include <stdint.h>

#define NN 8192
#define FD 256
#define LOG2E 1.44269504088896340736f
#define SPLIT 2
#define JSLICE (NN / SPLIT)      // 4096 j per gat block
#define NIT (JSLICE / 32)        // 128 B-iterations of 32 j (16 KB B-chunk each)
#define NADJ (JSLICE / 64)       // 64 adj chunks of 64 j (one chunk = 2 B-iters)

typedef __attribute__((ext_vector_type(8))) __bf16 bf16x8;
typedef __attribute__((ext_vector_type(4))) float f32x4;
typedef __attribute__((ext_vector_type(4))) int i32x4;

__device__ __forceinline__ unsigned short f2bf(float x) {
    unsigned u = __float_as_uint(x);
    u = u + 0x7fffu + ((u >> 16) & 1u);   // RNE; no NaNs in this problem
    return (unsigned short)(u >> 16);
}
__device__ __forceinline__ bf16x8 ld_bf8(const unsigned short* p) {
    uint4 v = *(const uint4*)p;
    return __builtin_bit_cast(bf16x8, v);
}
// pack two f32 -> (bf16(b)<<16)|bf16(a) by truncation, single v_perm
__device__ __forceinline__ unsigned pack_trunc2(float a, float b) {
    return __builtin_amdgcn_perm(__float_as_uint(b), __float_as_uint(a), 0x07060302u);
}
// Non-sinkable async global->LDS, 16 B/lane. HW uses wave-uniform LDS base + lane*16.
__device__ __forceinline__ void async_ld16(const void* g, void* lds) {
    __builtin_amdgcn_global_load_lds(
        (const __attribute__((address_space(1))) void*)g,
        (__attribute__((address_space(3))) void*)lds, 16, 0, 0);
}
// Non-temporal 16B load (native clang vector; HIP int4 struct rejected by builtin).
// adj streams 256 MB once; keep it out of L2 so the XCD-local PB slice stays resident.
__device__ __forceinline__ i32x4 ld_nt_i4(const int* p) {
    return __builtin_nontemporal_load((const i32x4*)p);
}

// ---------------- Kernel 0: WbT[f][k] = bf16(W[k][f]) ----------------
__global__ __launch_bounds__(256) void wtrans_kernel(const float* __restrict__ W,
                                                     unsigned short* __restrict__ WbT) {
    int idx = blockIdx.x * 256 + threadIdx.x;   // 65536 elems
    int k = idx >> 8, f = idx & 255;
    WbT[f * 256 + k] = f2bf(W[idx]);
}

// ---------------- Kernel 1: PB = MFMA-B-fragment-packed (h@W+b); fused f1/f2 ----------------
// PB unit (jc, fg, lane l=(cl,q)): 8 bf16 = Wh[j = jc*32 + q*8 .. +7][f = fg*16+cl].
__global__ __launch_bounds__(256) void gemm1_kernel(const float* __restrict__ h,
                                                    const unsigned short* __restrict__ WbT,
                                                    const float* __restrict__ bias,
                                                    const float* __restrict__ av,
                                                    unsigned short* __restrict__ PBu,
                                                    float* __restrict__ f1p,
                                                    float* __restrict__ f2p) {
    __shared__ float Wh_s[256 * 33];   // [f][i-local], +1 pad
    __shared__ float red_s[2 * 8 * 32];
    int t = threadIdx.x;
    int l = t & 63, w = t >> 6;
    int jc = (blockIdx.x & 7) * 32 + (blockIdx.x >> 3);
    int i0 = jc * 32;
    int fbase = w * 64;
    int cl = l & 15, q = l >> 4;

    f32x4 acc[2][4] = {};
    const float* hA0 = h + (size_t)(i0 + cl) * FD;
    const float* hA1 = h + (size_t)(i0 + 16 + cl) * FD;

    #pragma unroll
    for (int ks = 0; ks < 8; ++ks) {
        int kk = ks * 32 + q * 8;
        union { unsigned short u[8]; bf16x8 v; } ua0, ua1;
        float4 x0 = *(const float4*)(hA0 + kk);
        float4 x1 = *(const float4*)(hA0 + kk + 4);
        float4 y0 = *(const float4*)(hA1 + kk);
        float4 y1 = *(const float4*)(hA1 + kk + 4);
        ua0.u[0]=f2bf(x0.x); ua0.u[1]=f2bf(x0.y); ua0.u[2]=f2bf(x0.z); ua0.u[3]=f2bf(x0.w);
        ua0.u[4]=f2bf(x1.x); ua0.u[5]=f2bf(x1.y); ua0.u[6]=f2bf(x1.z); ua0.u[7]=f2bf(x1.w);
        ua1.u[0]=f2bf(y0.x); ua1.u[1]=f2bf(y0.y); ua1.u[2]=f2bf(y0.z); ua1.u[3]=f2bf(y0.w);
        ua1.u[4]=f2bf(y1.x); ua1.u[5]=f2bf(y1.y); ua1.u[6]=f2bf(y1.z); ua1.u[7]=f2bf(y1.w);
        #pragma unroll
        for (int bg = 0; bg < 4; ++bg) {
            bf16x8 bF = ld_bf8(WbT + (fbase + bg * 16 + cl) * 256 + kk);
            acc[0][bg] = __builtin_amdgcn_mfma_f32_16x16x32_bf16(ua0.v, bF, acc[0][bg], 0, 0, 0);
            acc[1][bg] = __builtin_amdgcn_mfma_f32_16x16x32_bf16(ua1.v, bF, acc[1][bg], 0, 0, 0);
        }
    }

    // C layout: col = lane&15, row = (lane>>4)*4 + reg   [m89-verified]
    #pragma unroll
    for (int mt = 0; mt < 2; ++mt)
        #pragma unroll
        for (int bg = 0; bg < 4; ++bg)
            #pragma unroll
            for (int e = 0; e < 4; ++e) {
                int il = mt * 16 + q * 4 + e;
                int fl = fbase + bg * 16 + cl;
                Wh_s[fl * 33 + il] = acc[mt][bg][e] + bias[fl];
            }
    __syncthreads();
    {   // emit packed-B fragments for chunk jc
        size_t jcBase = (size_t)jc * 8192;   // 16 fg * 64 lanes * 8 elems
        #pragma unroll
        for (int u = 0; u < 4; ++u) {
            int fg = u * 4 + (t >> 6);
            int ll = t & 63;
            int c2 = ll & 15, q2 = ll >> 4;
            const float* src = &Wh_s[(fg * 16 + c2) * 33 + q2 * 8];
            union { unsigned short us[8]; uint4 v; } p;
            #pragma unroll
            for (int e = 0; e < 8; ++e) p.us[e] = f2bf(src[e]);
            *(uint4*)(PBu + jcBase + fg * 512 + ll * 8) = p.v;
        }
    }
    // fused f1/f2 partials: thread t -> i = t&31, f-chunk = t>>5 (32 f's)
    {
        int i = t & 31, fc = t >> 5;
        float s1 = 0.f, s2 = 0.f;
        #pragma unroll
        for (int fo = 0; fo < 32; ++fo) {
            int f = fc * 32 + fo;
            float wv = Wh_s[f * 33 + i];
            s1 += wv * av[f];
            s2 += wv * av[256 + f];
        }
        red_s[fc * 32 + i] = s1;
        red_s[256 + fc * 32 + i] = s2;
    }
    __syncthreads();
    if (t < 32) {
        float s = 0.f;
        #pragma unroll
        for (int fc = 0; fc < 8; ++fc) s += red_s[fc * 32 + t];
        f1p[i0 + t] = s * LOG2E;
    } else if (t < 64) {
        int i = t - 32;
        float s = 0.f;
        #pragma unroll
        for (int fc = 0; fc < 8; ++fc) s += red_s[256 + fc * 32 + i];
        f2p[i0 + i] = s * LOG2E;
    }
}

// ---------------- Kernel 2: megafused GAT — SPLIT=2, 512-thr blocks, row×f wave split ----------------
// Grid = 128 strips x SPLIT(=2) = 256 blocks = 1 block/CU; block = 512 thr (8 waves) ->
// still 8 waves/CU. Wave w: row-group rgrp=w>>1 (16 rows), f-half fh=w&1 (128 f).
// Per wave-iter: 8 B-frag ds_read_b128 (8 KB, HALF of the SPLIT=4 layout) + 8 exp2
// (P duplicated across the two f-half waves — VALU is cheap) + 8(+1) MFMA.
// adj: wave w loads rows w*8..+7 of each 64-j chunk (2 nt dwordx4/lane); ballot ->
// 4-deep mask ring; consumers are waves 2*rgrp(+1) — cross-wave, ordered by the entry
// __syncthreads (masks for iter g written at body g-1).
__global__ __launch_bounds__(512, 2) void gat_kernel(const int* __restrict__ adj,
                                                     const unsigned short* __restrict__ PBu,
                                                     const float* __restrict__ f1p,
                                                     const float* __restrict__ f2p,
                                                     float* __restrict__ num,
                                                     float* __restrict__ den) {
    __shared__ __align__(16) unsigned short Bs[2][8192];       // 32 KB dbuf (16 KB/chunk)
    __shared__ unsigned mask_b[4][64];                         // 1 KB ring (4 B-iters deep)
    __shared__ float f2_s[JSLICE];                             // 16 KB

    int t = threadIdx.x;
    int l = t & 63, w = t >> 6;          // 8 waves
    int s = blockIdx.x & (SPLIT - 1);    // j-split
    int strip = blockIdx.x / SPLIT;
    int i0b = strip * 64;                // block's 64 rows
    int j0 = s * JSLICE;
    int jw0 = j0 / 32;
    int cl = l & 15, q = l >> 4;
    int rgrp = w >> 1;                   // row-group: rows i0b + rgrp*16 .. +15
    int fh = w & 1;                      // f-half: cols fh*128 .. +127

    // ---- prologue: f2 slice (4096 floats), B chunk 0 (async), adj chunk 0 (wide) ----
    #pragma unroll
    for (int k = 0; k < 2; ++k)
        *(float4*)&f2_s[k * 2048 + t * 4] = *(const float4*)(f2p + j0 + k * 2048 + t * 4);

    const char* pbBase = (const char*)(PBu + (size_t)jw0 * 8192);
    #pragma unroll
    for (int k = 0; k < 2; ++k)
        async_ld16(pbBase + k * 8192 + t * 16, (char*)&Bs[0][0] + k * 8192 + t * 16);

    // adj: wave w covers rows w*8 + ld*4 + (l>>4), ld in {0,1}; j = j0 + (l&15)*4 .. +3
    const int* abase = adj + (size_t)(i0b + w * 8 + (l >> 4)) * NN + j0 + (l & 15) * 4;
    i32x4 A0 = ld_nt_i4(abase);
    i32x4 A1 = ld_nt_i4(abase + 4 * NN);

    float f1v = f1p[i0b + rgrp * 16 + cl];

    __syncthreads();   // drains f2, B(0), adj chunk 0, f1v; orders f2_s across waves

    // ballot adj chunk 0 -> mask slots 0,1 (rows w*8..+7 of this wave)
    {
        int word = (l >> 3) & 1;           // which 32-j word of this row
        int sh = 4 * (l & 7);              // nibble position within word
        int rsub = l >> 4;                 // row-within-load-group
        #pragma unroll
        for (int ld = 0; ld < 2; ++ld) {
            i32x4 A = ld == 0 ? A0 : A1;
            unsigned n = (unsigned)(A[0] > 0) | ((unsigned)(A[1] > 0) << 1)
                       | ((unsigned)(A[2] > 0) << 2) | ((unsigned)(A[3] > 0) << 3);
            unsigned v = n << sh;
            v |= __shfl_xor(v, 1);
            v |= __shfl_xor(v, 2);
            v |= __shfl_xor(v, 4);
            if ((l & 7) == 0)
                mask_b[word][w * 8 + ld * 4 + rsub] = v;
        }
    }

    // all-ones B fragment (bf16 1.0 = 0x3F80) for the rowsum MFMA
    const bf16x8 onesB = __builtin_bit_cast(bf16x8,
        make_uint4(0x3F803F80u, 0x3F803F80u, 0x3F803F80u, 0x3F803F80u));

    f32x4 acc[8] = {};
    f32x4 accR = {};                     // rowsum accumulator

    #pragma unroll 1
    for (int g = 0; g < NIT; ++g) {
        __syncthreads();   // drains B(g) staging + adj loads issued at body g-1; orders masks

        if (g + 1 < NIT) {
            // stage B(g+1) into the buffer last read at iteration g-1
            const char* src = pbBase + (size_t)(g + 1) * 16384;
            char* dst = (char*)&Bs[(g + 1) & 1][0];
            #pragma unroll
            for (int k = 0; k < 2; ++k)
                async_ld16(src + k * 8192 + t * 16, dst + k * 8192 + t * 16);
        }

        if ((g & 1) == 0) {
            // even body: issue adj chunk (g/2 + 1) wide nt loads (drained by next entry sync)
            int c1 = g / 2 + 1;
            if (c1 < NADJ) {
                int jo = c1 * 64;
                A0 = ld_nt_i4(abase + jo);
                A1 = ld_nt_i4(abase + 4 * NN + jo);
            }
        } else {
            // odd body: ballot adj chunk (g+1)/2 -> mask slots (g+1)&3, (g+2)&3
            int c1 = (g + 1) / 2;
            if (c1 < NADJ) {
                int word = (l >> 3) & 1;
                int slot = (g + 1 + word) & 3;
                int sh = 4 * (l & 7);
                int rsub = l >> 4;
                #pragma unroll
                for (int ld = 0; ld < 2; ++ld) {
                    i32x4 A = ld == 0 ? A0 : A1;
                    unsigned n = (unsigned)(A[0] > 0) | ((unsigned)(A[1] > 0) << 1)
                               | ((unsigned)(A[2] > 0) << 2) | ((unsigned)(A[3] > 0) << 3);
                    unsigned v = n << sh;
                    v |= __shfl_xor(v, 1);
                    v |= __shfl_xor(v, 2);
                    v |= __shfl_xor(v, 4);
                    if ((l & 7) == 0)
                        mask_b[slot][w * 8 + ld * 4 + rsub] = v;
                }
            }
        }

        // ---- compute chunk g (masks written >=1 iter ago; B staged last iter) ----
        unsigned mw = mask_b[g & 3][rgrp * 16 + cl];
        float4 F0 = *(const float4*)&f2_s[g * 32 + q * 8];
        float4 F1 = *(const float4*)&f2_s[g * 32 + q * 8 + 4];

        unsigned bits = mw >> (q * 8);
        float fe[8] = {F0.x, F0.y, F0.z, F0.w, F1.x, F1.y, F1.z, F1.w};
        float wv[8];
        #pragma unroll
        for (int e = 0; e < 8; ++e) {
            float sv = f1v + fe[e];
            sv = fmaxf(sv, 0.2f * sv);           // leaky_relu, pre-scaled by log2e
            float x = __builtin_amdgcn_exp2f(sv);
            x = (bits >> e) & 1 ? x : 0.f;
            wv[e] = x;
        }
        union { unsigned uu[4]; bf16x8 v; } af;
        af.uu[0] = pack_trunc2(wv[0], wv[1]);
        af.uu[1] = pack_trunc2(wv[2], wv[3]);
        af.uu[2] = pack_trunc2(wv[4], wv[5]);
        af.uu[3] = pack_trunc2(wv[6], wv[7]);

        const unsigned short* bu = &Bs[g & 1][0] + l * 8;
        #pragma unroll
        for (int b = 0; b < 8; ++b) {
            bf16x8 B = ld_bf8(bu + (fh * 8 + b) * 512);
            acc[b] = __builtin_amdgcn_mfma_f32_16x16x32_bf16(af.v, B, acc[b], 0, 0, 0);
        }
        if (fh == 0)
            accR = __builtin_amdgcn_mfma_f32_16x16x32_bf16(af.v, onesB, accR, 0, 0, 0);
    }

    // denominator: accR C layout row = q*4+e, every col identical; fh==0, cl==0 lanes write
    if (fh == 0 && cl == 0) {
        #pragma unroll
        for (int e = 0; e < 4; ++e)
            den[(size_t)s * NN + i0b + rgrp * 16 + q * 4 + e] = accR[e];
    }

    // partial numerator: C layout row r = q*4+e, col = (fh*8+b)*16+cl
    float* nrow = num + (size_t)s * NN * FD;
    #pragma unroll
    for (int e = 0; e < 4; ++e) {
        int r = i0b + rgrp * 16 + q * 4 + e;
        #pragma unroll
        for (int b = 0; b < 8; ++b)
            nrow[(size_t)r * FD + (fh * 8 + b) * 16 + cl] = acc[b][e];
    }
}

// ---------------- Kernel 3: combine j-split partials ----------------
__global__ __launch_bounds__(256) void combine_kernel(const float* __restrict__ num,
                                                      const float* __restrict__ den,
                                                      float* __restrict__ out) {
    int idx = blockIdx.x * 256 + threadIdx.x;   // 2M elems; i uniform per block
    int i = idx >> 8;
    float nsum = 0.f, dsum = 0.f;
    #pragma unroll
    for (int s = 0; s < SPLIT; ++s) {
        nsum += num[(size_t)s * NN * FD + idx];
        dsum += den[(size_t)s * NN + i];
    }
    out[idx] = nsum / dsum;
}

extern "C" void kernel_launch(void* const* d_in, const int* in_sizes, int n_in,
                              void* d_out, int out_size, void* d_ws, size_t ws_size,
                              hipStream_t stream) {
    const float* h   = (const float*)d_in[0];
    const int*   adj = (const int*)d_in[1];
    const float* W   = (const float*)d_in[2];
    const float* b   = (const float*)d_in[3];
    const float* a   = (const float*)d_in[4];
    float* out = (float*)d_out;

    char* ws = (char*)d_ws;
    unsigned short* PBu = (unsigned short*)ws;                          // 4 MB packed Wh fragments
    unsigned short* WbT = (unsigned short*)(ws + (4u << 20));           // 128 KB
    float* f1p = (float*)(ws + (4u << 20) + (128u << 10));              // 32 KB
    float* f2p = f1p + NN;                                              // 32 KB
    float* den = f2p + NN;                                              // SPLIT*NN f32 = 64 KB
    float* num = (float*)(ws + (24u << 20));                            // SPLIT*8 MB = 16 MB

    wtrans_kernel<<<256, 256, 0, stream>>>(W, WbT);
    gemm1_kernel<<<256, 256, 0, stream>>>(h, WbT, b, a, PBu, f1p, f2p);
    gat_kernel<<<128 * SPLIT, 512, 0, stream>>>(adj, PBu, f1p, f2p, num, den);
    combine_kernel<<<NN * FD / 256, 256, 0, stream>>>(num, den, out);
}

// Round 6
// 420.471 us; speedup vs baseline: 1.0743x; 1.0743x over previous
//
#include <hip/hip_runtime.h>
#include <stdint.h>

#define NN 8192
#define FD 256
#define LOG2E 1.44269504088896340736f
#define SPLIT 4
#define JSLICE (NN / SPLIT)      // 2048 j per gat block
#define NIT (JSLICE / 32)        // 64 B-iterations of 32 j (16 KB B-chunk each)
#define NADJ (JSLICE / 64)       // 32 adj chunks of 64 j (one chunk = 2 B-iters)

typedef __attribute__((ext_vector_type(8))) __bf16 bf16x8;
typedef __attribute__((ext_vector_type(4))) float f32x4;
typedef __attribute__((ext_vector_type(4))) int i32x4;

__device__ __forceinline__ unsigned short f2bf(float x) {
    unsigned u = __float_as_uint(x);
    u = u + 0x7fffu + ((u >> 16) & 1u);   // RNE; no NaNs in this problem
    return (unsigned short)(u >> 16);
}
__device__ __forceinline__ bf16x8 ld_bf8(const unsigned short* p) {
    uint4 v = *(const uint4*)p;
    return __builtin_bit_cast(bf16x8, v);
}
// pack two f32 -> (bf16(b)<<16)|bf16(a) by truncation, single v_perm
__device__ __forceinline__ unsigned pack_trunc2(float a, float b) {
    return __builtin_amdgcn_perm(__float_as_uint(b), __float_as_uint(a), 0x07060302u);
}
// Non-sinkable async global->LDS, 16 B/lane. HW uses wave-uniform LDS base + lane*16.
__device__ __forceinline__ void async_ld16(const void* g, void* lds) {
    __builtin_amdgcn_global_load_lds(
        (const __attribute__((address_space(1))) void*)g,
        (__attribute__((address_space(3))) void*)lds, 16, 0, 0);
}
// Non-temporal 16B loads (native clang vector; HIP struct vecs rejected by builtin).
// Stream-once data stays out of L2.
__device__ __forceinline__ i32x4 ld_nt_i4(const int* p) {
    return __builtin_nontemporal_load((const i32x4*)p);
}
__device__ __forceinline__ f32x4 ld_nt_f4(const float* p) {
    return __builtin_nontemporal_load((const f32x4*)p);
}

// ---------------- Kernel 0: WbT[f][k] = bf16(W[k][f]) ----------------
__global__ __launch_bounds__(256) void wtrans_kernel(const float* __restrict__ W,
                                                     unsigned short* __restrict__ WbT) {
    int idx = blockIdx.x * 256 + threadIdx.x;   // 65536 elems
    int k = idx >> 8, f = idx & 255;
    WbT[f * 256 + k] = f2bf(W[idx]);
}

// ---------------- Kernel 1: PB = MFMA-B-fragment-packed (h@W+b); fused f1/f2 ----------------
// PB unit (jc, fg, lane l=(cl,q)): 8 bf16 = Wh[j = jc*32 + q*8 .. +7][f = fg*16+cl].
__global__ __launch_bounds__(256) void gemm1_kernel(const float* __restrict__ h,
                                                    const unsigned short* __restrict__ WbT,
                                                    const float* __restrict__ bias,
                                                    const float* __restrict__ av,
                                                    unsigned short* __restrict__ PBu,
                                                    float* __restrict__ f1p,
                                                    float* __restrict__ f2p) {
    __shared__ float Wh_s[256 * 33];   // [f][i-local], +1 pad
    __shared__ float red_s[2 * 8 * 32];
    int t = threadIdx.x;
    int l = t & 63, w = t >> 6;
    int jc = (blockIdx.x & 7) * 32 + (blockIdx.x >> 3);
    int i0 = jc * 32;
    int fbase = w * 64;
    int cl = l & 15, q = l >> 4;

    f32x4 acc[2][4] = {};
    const float* hA0 = h + (size_t)(i0 + cl) * FD;
    const float* hA1 = h + (size_t)(i0 + 16 + cl) * FD;

    #pragma unroll
    for (int ks = 0; ks < 8; ++ks) {
        int kk = ks * 32 + q * 8;
        union { unsigned short u[8]; bf16x8 v; } ua0, ua1;
        float4 x0 = *(const float4*)(hA0 + kk);
        float4 x1 = *(const float4*)(hA0 + kk + 4);
        float4 y0 = *(const float4*)(hA1 + kk);
        float4 y1 = *(const float4*)(hA1 + kk + 4);
        ua0.u[0]=f2bf(x0.x); ua0.u[1]=f2bf(x0.y); ua0.u[2]=f2bf(x0.z); ua0.u[3]=f2bf(x0.w);
        ua0.u[4]=f2bf(x1.x); ua0.u[5]=f2bf(x1.y); ua0.u[6]=f2bf(x1.z); ua0.u[7]=f2bf(x1.w);
        ua1.u[0]=f2bf(y0.x); ua1.u[1]=f2bf(y0.y); ua1.u[2]=f2bf(y0.z); ua1.u[3]=f2bf(y0.w);
        ua1.u[4]=f2bf(y1.x); ua1.u[5]=f2bf(y1.y); ua1.u[6]=f2bf(y1.z); ua1.u[7]=f2bf(y1.w);
        #pragma unroll
        for (int bg = 0; bg < 4; ++bg) {
            bf16x8 bF = ld_bf8(WbT + (fbase + bg * 16 + cl) * 256 + kk);
            acc[0][bg] = __builtin_amdgcn_mfma_f32_16x16x32_bf16(ua0.v, bF, acc[0][bg], 0, 0, 0);
            acc[1][bg] = __builtin_amdgcn_mfma_f32_16x16x32_bf16(ua1.v, bF, acc[1][bg], 0, 0, 0);
        }
    }

    // C layout: col = lane&15, row = (lane>>4)*4 + reg   [m89-verified]
    #pragma unroll
    for (int mt = 0; mt < 2; ++mt)
        #pragma unroll
        for (int bg = 0; bg < 4; ++bg)
            #pragma unroll
            for (int e = 0; e < 4; ++e) {
                int il = mt * 16 + q * 4 + e;
                int fl = fbase + bg * 16 + cl;
                Wh_s[fl * 33 + il] = acc[mt][bg][e] + bias[fl];
            }
    __syncthreads();
    {   // emit packed-B fragments for chunk jc
        size_t jcBase = (size_t)jc * 8192;   // 16 fg * 64 lanes * 8 elems
        #pragma unroll
        for (int u = 0; u < 4; ++u) {
            int fg = u * 4 + (t >> 6);
            int ll = t & 63;
            int c2 = ll & 15, q2 = ll >> 4;
            const float* src = &Wh_s[(fg * 16 + c2) * 33 + q2 * 8];
            union { unsigned short us[8]; uint4 v; } p;
            #pragma unroll
            for (int e = 0; e < 8; ++e) p.us[e] = f2bf(src[e]);
            *(uint4*)(PBu + jcBase + fg * 512 + ll * 8) = p.v;
        }
    }
    // fused f1/f2 partials: thread t -> i = t&31, f-chunk = t>>5 (32 f's)
    {
        int i = t & 31, fc = t >> 5;
        float s1 = 0.f, s2 = 0.f;
        #pragma unroll
        for (int fo = 0; fo < 32; ++fo) {
            int f = fc * 32 + fo;
            float wv = Wh_s[f * 33 + i];
            s1 += wv * av[f];
            s2 += wv * av[256 + f];
        }
        red_s[fc * 32 + i] = s1;
        red_s[256 + fc * 32 + i] = s2;
    }
    __syncthreads();
    if (t < 32) {
        float s = 0.f;
        #pragma unroll
        for (int fc = 0; fc < 8; ++fc) s += red_s[fc * 32 + t];
        f1p[i0 + t] = s * LOG2E;
    } else if (t < 64) {
        int i = t - 32;
        float s = 0.f;
        #pragma unroll
        for (int fc = 0; fc < 8; ++fc) s += red_s[256 + fc * 32 + i];
        f2p[i0 + i] = s * LOG2E;
    }
}

// ---------------- Kernel 2: megafused GAT — SPLIT=4, wide nt adj reads ----------------
// Grid = 128 strips x SPLIT(=4); block = 256 thr (4 waves), 64 rows x 2048 j, 2 blk/CU
// = 8 waves/CU. (R5 lesson: 1 blk/CU couples all waves to each barrier's vmcnt drain —
// keep >=2 independent blocks per CU.)
// adj read in 64-j chunks via nontemporal dwordx4 (4 rows x 64 j per load; 256 B
// contiguous per row; L2-bypass keeps XCD-local PB slice resident).
// Mask assembly: per-lane 4-bit nibble -> OR across 8-lane groups (3 shfl_xor) -> 32-bit
// row-mask words into a 4-deep wave-private LDS ring.
// Schedule: even B-iter body issues adj chunk (g/2+1); next entry __syncthreads drains
// (full-iteration cover >> HBM latency); odd body ballots.
__global__ __launch_bounds__(256, 4) void gat_kernel(const int* __restrict__ adj,
                                                     const unsigned short* __restrict__ PBu,
                                                     const float* __restrict__ f1p,
                                                     const float* __restrict__ f2p,
                                                     float* __restrict__ num,
                                                     float* __restrict__ den) {
    __shared__ __align__(16) unsigned short Bs[2][8192];       // 32 KB dbuf (16 KB/chunk)
    __shared__ unsigned mask_b[4][64];                         // 1 KB ring (4 B-iters deep)
    __shared__ float f2_s[JSLICE];                             // 8 KB

    int t = threadIdx.x;
    int l = t & 63, w = t >> 6;
    int s = blockIdx.x & (SPLIT - 1);    // j-split
    int strip = blockIdx.x / SPLIT;
    int i0b = strip * 64;                // block's 64 rows
    int j0 = s * JSLICE;
    int jw0 = j0 / 32;
    int cl = l & 15, q = l >> 4;

    // ---- prologue: f2 slice (2048 floats), B chunk 0 (async), adj chunk 0 (wide) ----
    #pragma unroll
    for (int k = 0; k < JSLICE / 1024; ++k)
        *(float4*)&f2_s[k * 1024 + t * 4] = *(const float4*)(f2p + j0 + k * 1024 + t * 4);

    const char* pbBase = (const char*)(PBu + (size_t)jw0 * 8192);
    #pragma unroll
    for (int k = 0; k < 4; ++k)
        async_ld16(pbBase + k * 4096 + t * 16, (char*)&Bs[0][0] + k * 4096 + t * 16);

    // wide-adj base: lane l covers row i0b + w*16 + ld*4 + (l>>4), j = j0 + (l&15)*4 .. +3
    const int* abase = adj + (size_t)(i0b + w * 16 + (l >> 4)) * NN + j0 + (l & 15) * 4;
    i32x4 A0 = ld_nt_i4(abase + 0 * 4 * NN);
    i32x4 A1 = ld_nt_i4(abase + 1 * 4 * NN);
    i32x4 A2 = ld_nt_i4(abase + 2 * 4 * NN);
    i32x4 A3 = ld_nt_i4(abase + 3 * 4 * NN);

    float f1v = f1p[i0b + w * 16 + cl];  // wave w owns rows i0b + w*16 .. +15

    __syncthreads();   // drains f2, B(0), adj chunk 0, f1v; orders f2_s across waves

    // ballot adj chunk 0 -> mask slots 0,1 (wave-private rows)
    {
        int word = (l >> 3) & 1;           // which 32-j word of this row
        int sh = 4 * (l & 7);              // nibble position within word
        int rsub = l >> 4;                 // row-within-load-group
        #pragma unroll
        for (int ld = 0; ld < 4; ++ld) {
            i32x4 A = ld == 0 ? A0 : ld == 1 ? A1 : ld == 2 ? A2 : A3;
            unsigned n = (unsigned)(A[0] > 0) | ((unsigned)(A[1] > 0) << 1)
                       | ((unsigned)(A[2] > 0) << 2) | ((unsigned)(A[3] > 0) << 3);
            unsigned v = n << sh;
            v |= __shfl_xor(v, 1);
            v |= __shfl_xor(v, 2);
            v |= __shfl_xor(v, 4);
            if ((l & 7) == 0)
                mask_b[word][w * 16 + ld * 4 + rsub] = v;
        }
    }

    // all-ones B fragment (bf16 1.0 = 0x3F80) for the rowsum MFMA
    const bf16x8 onesB = __builtin_bit_cast(bf16x8,
        make_uint4(0x3F803F80u, 0x3F803F80u, 0x3F803F80u, 0x3F803F80u));

    f32x4 acc[16] = {};
    f32x4 accR = {};                     // rowsum accumulator

    #pragma unroll 1
    for (int g = 0; g < NIT; ++g) {
        __syncthreads();   // drains B(g) staging + adj loads issued at body g-1

        if (g + 1 < NIT) {
            // stage B(g+1) into the buffer last read at iteration g-1
            const char* src = pbBase + (size_t)(g + 1) * 16384;
            char* dst = (char*)&Bs[(g + 1) & 1][0];
            #pragma unroll
            for (int k = 0; k < 4; ++k)
                async_ld16(src + k * 4096 + t * 16, dst + k * 4096 + t * 16);
        }

        if ((g & 1) == 0) {
            // even body: issue adj chunk (g/2 + 1) wide loads (drained by next entry sync)
            int c1 = g / 2 + 1;
            if (c1 < NADJ) {
                int jo = c1 * 64;
                A0 = ld_nt_i4(abase + 0 * 4 * NN + jo);
                A1 = ld_nt_i4(abase + 1 * 4 * NN + jo);
                A2 = ld_nt_i4(abase + 2 * 4 * NN + jo);
                A3 = ld_nt_i4(abase + 3 * 4 * NN + jo);
            }
        } else {
            // odd body: ballot adj chunk (g+1)/2 -> mask slots (g+1)&3, (g+2)&3
            int c1 = (g + 1) / 2;
            if (c1 < NADJ) {
                int word = (l >> 3) & 1;
                int slot = (g + 1 + word) & 3;
                int sh = 4 * (l & 7);
                int rsub = l >> 4;
                #pragma unroll
                for (int ld = 0; ld < 4; ++ld) {
                    i32x4 A = ld == 0 ? A0 : ld == 1 ? A1 : ld == 2 ? A2 : A3;
                    unsigned n = (unsigned)(A[0] > 0) | ((unsigned)(A[1] > 0) << 1)
                               | ((unsigned)(A[2] > 0) << 2) | ((unsigned)(A[3] > 0) << 3);
                    unsigned v = n << sh;
                    v |= __shfl_xor(v, 1);
                    v |= __shfl_xor(v, 2);
                    v |= __shfl_xor(v, 4);
                    if ((l & 7) == 0)
                        mask_b[slot][w * 16 + ld * 4 + rsub] = v;
                }
            }
        }

        // ---- compute chunk g (masks written >=1 iter ago, same wave; B staged last iter) ----
        unsigned mw = mask_b[g & 3][w * 16 + cl];
        float4 F0 = *(const float4*)&f2_s[g * 32 + q * 8];
        float4 F1 = *(const float4*)&f2_s[g * 32 + q * 8 + 4];

        unsigned bits = mw >> (q * 8);
        float fe[8] = {F0.x, F0.y, F0.z, F0.w, F1.x, F1.y, F1.z, F1.w};
        float wv[8];
        #pragma unroll
        for (int e = 0; e < 8; ++e) {
            float sv = f1v + fe[e];
            sv = fmaxf(sv, 0.2f * sv);           // leaky_relu, pre-scaled by log2e
            float x = __builtin_amdgcn_exp2f(sv);
            x = (bits >> e) & 1 ? x : 0.f;
            wv[e] = x;
        }
        union { unsigned uu[4]; bf16x8 v; } af;
        af.uu[0] = pack_trunc2(wv[0], wv[1]);
        af.uu[1] = pack_trunc2(wv[2], wv[3]);
        af.uu[2] = pack_trunc2(wv[4], wv[5]);
        af.uu[3] = pack_trunc2(wv[6], wv[7]);

        const unsigned short* bu = &Bs[g & 1][0] + l * 8;
        #pragma unroll
        for (int fg = 0; fg < 16; ++fg) {
            bf16x8 B = ld_bf8(bu + fg * 512);
            acc[fg] = __builtin_amdgcn_mfma_f32_16x16x32_bf16(af.v, B, acc[fg], 0, 0, 0);
        }
        accR = __builtin_amdgcn_mfma_f32_16x16x32_bf16(af.v, onesB, accR, 0, 0, 0);
    }

    // denominator: accR C layout row = q*4+e, every col identical; cl==0 lanes write
    if (cl == 0) {
        #pragma unroll
        for (int e = 0; e < 4; ++e)
            den[(size_t)s * NN + i0b + w * 16 + q * 4 + e] = accR[e];
    }

    // partial numerator: C layout row r = q*4+e, col = fg*16+cl
    float* nrow = num + (size_t)s * NN * FD;
    #pragma unroll
    for (int e = 0; e < 4; ++e) {
        int r = i0b + w * 16 + q * 4 + e;
        #pragma unroll
        for (int fg = 0; fg < 16; ++fg)
            nrow[(size_t)r * FD + fg * 16 + cl] = acc[fg][e];
    }
}

// ---------------- Kernel 3: combine j-split partials (float4-vectorized, nt reads) ----------------
__global__ __launch_bounds__(256) void combine_kernel(const float* __restrict__ num,
                                                      const float* __restrict__ den,
                                                      float* __restrict__ out) {
    int idx4 = blockIdx.x * 256 + threadIdx.x;   // 512K float4 elems; i uniform per block
    int base = idx4 * 4;
    int i = base >> 8;                           // 4 elems lie in one row (FD % 4 == 0)
    f32x4 nsum = {};
    float dsum = 0.f;
    #pragma unroll
    for (int s = 0; s < SPLIT; ++s) {
        f32x4 v = ld_nt_f4(num + (size_t)s * NN * FD + base);
        nsum += v;
        dsum += den[(size_t)s * NN + i];
    }
    float r = 1.0f / dsum;
    f32x4 o = nsum * r;
    *(f32x4*)(out + base) = o;
}

extern "C" void kernel_launch(void* const* d_in, const int* in_sizes, int n_in,
                              void* d_out, int out_size, void* d_ws, size_t ws_size,
                              hipStream_t stream) {
    const float* h   = (const float*)d_in[0];
    const int*   adj = (const int*)d_in[1];
    const float* W   = (const float*)d_in[2];
    const float* b   = (const float*)d_in[3];
    const float* a   = (const float*)d_in[4];
    float* out = (float*)d_out;

    char* ws = (char*)d_ws;
    unsigned short* PBu = (unsigned short*)ws;                          // 4 MB packed Wh fragments
    unsigned short* WbT = (unsigned short*)(ws + (4u << 20));           // 128 KB
    float* f1p = (float*)(ws + (4u << 20) + (128u << 10));              // 32 KB
    float* f2p = f1p + NN;                                              // 32 KB
    float* den = f2p + NN;                                              // SPLIT*NN f32 = 128 KB
    float* num = (float*)(ws + (24u << 20));                            // SPLIT*8 MB = 32 MB

    wtrans_kernel<<<256, 256, 0, stream>>>(W, WbT);
    gemm1_kernel<<<256, 256, 0, stream>>>(h, WbT, b, a, PBu, f1p, f2p);
    gat_kernel<<<128 * SPLIT, 256, 0, stream>>>(adj, PBu, f1p, f2p, num, den);
    combine_kernel<<<NN * FD / 1024, 256, 0, stream>>>(num, den, out);
}